// Round 3
// baseline (220.370 us; speedup 1.0000x reference)
//
#include <hip/hip_runtime.h>

typedef __attribute__((ext_vector_type(8))) unsigned short ushort8;
typedef __attribute__((ext_vector_type(8))) short short8;
typedef __attribute__((ext_vector_type(4))) float f32x4;

#define M_DIM 8192
#define N_DIM 2048
#define K_DIM 2048
#define BM 256
#define BN 256
#define BK 64
#define NT (K_DIM / BK)   // 32 k-tiles

// Module-scope barrier counter: zero-initialized at load. Every dispatch adds
// exactly 256, so the counter is ≡0 (mod 256) at each replay start and the
// generation arithmetic below stays aligned across graph replays. No reset
// kernel / memset needed.
__device__ unsigned int g_bar = 0;

// ---- fp32 -> bf16 (RNE) ----
__device__ __forceinline__ unsigned short f32_to_bf16(float f) {
  unsigned int u = __float_as_uint(f);
  u += 0x7fffu + ((u >> 16) & 1u);
  return (unsigned short)(u >> 16);
}

__device__ __forceinline__ void gload_lds16(const unsigned short* g, unsigned short* l) {
  __builtin_amdgcn_global_load_lds(
      (const __attribute__((address_space(1))) void*)g,
      (__attribute__((address_space(3))) void*)l,
      16, 0, 0);
}

// Single-dispatch fused kernel: [cast f32->bf16] -> device barrier -> [gemm].
// Round-3 change: the separate cast kernel + second launch are gone. 256 blocks
// = 1/CU (128KB LDS) -> all co-resident -> in-kernel device-scope barrier is
// deadlock-free. Cast is XCD-affine for A: each block casts A-rows consumed by
// its own XCD, so bf16 A is warm in the consumer's local L2 when the gemm
// stage starts. Gemm stage is the verified round-2 kernel, unchanged.
__global__ void __launch_bounds__(512, 2) gemm_fused(
    const float* __restrict__ x,
    const float* __restrict__ W,
    const float* __restrict__ bias,
    float* __restrict__ C,
    unsigned short* __restrict__ xb,
    unsigned short* __restrict__ Wb) {
  __shared__ unsigned short lds[2 * 32768];   // [buf][A 16384 | B 16384] elems

  const int tid  = threadIdx.x;
  const int lane = tid & 63;
  const int wave = tid >> 6;
  const int wm   = wave & 1;     // m-half (2)
  const int wn   = wave >> 1;    // n-quarter (4)

  // Bijective A-resident remap: 256 blocks = 32 m-tiles x 8 n-tiles.
  const int blk = blockIdx.x;
  const int xcd = blk & 7;
  const int bi  = blk >> 3;                 // 0..31 within XCD
  const int sub = bi >> 2;                  // 0..7 (also the n-tile index)
  const int bm0 = (xcd * 4 + (bi & 3)) * BM;
  const int bn0 = sub * BN;

  // ================= stage 0: cast f32 -> bf16 =================
  // A: the 8 blocks sharing this (xcd, m-tile) each cast 32 of its 256 rows
  // -> every m-tile cast exactly once, by blocks on the XCD that consumes it.
  {
    const size_t abase = (size_t)(bm0 + sub * 32) * K_DIM;   // 32 rows * 2048
#pragma unroll
    for (int it = 0; it < 16; ++it) {
      size_t o = abase + (size_t)(it * 512 + tid) * 8;
      float4 a = *(const float4*)(x + o);
      float4 b = *(const float4*)(x + o + 4);
      ushort8 r;
      r[0] = f32_to_bf16(a.x); r[1] = f32_to_bf16(a.y);
      r[2] = f32_to_bf16(a.z); r[3] = f32_to_bf16(a.w);
      r[4] = f32_to_bf16(b.x); r[5] = f32_to_bf16(b.y);
      r[6] = f32_to_bf16(b.z); r[7] = f32_to_bf16(b.w);
      *(ushort8*)(xb + o) = r;
    }
    // B: flat 1/256 slice (2048*2048 / 256 = 16384 elems).
    const size_t bbase = (size_t)blk * 16384;
#pragma unroll
    for (int it = 0; it < 4; ++it) {
      size_t o = bbase + (size_t)(it * 512 + tid) * 8;
      float4 a = *(const float4*)(W + o);
      float4 b = *(const float4*)(W + o + 4);
      ushort8 r;
      r[0] = f32_to_bf16(a.x); r[1] = f32_to_bf16(a.y);
      r[2] = f32_to_bf16(a.z); r[3] = f32_to_bf16(a.w);
      r[4] = f32_to_bf16(b.x); r[5] = f32_to_bf16(b.y);
      r[6] = f32_to_bf16(b.z); r[7] = f32_to_bf16(b.w);
      *(ushort8*)(Wb + o) = r;
    }
  }

  // ================= device-scope barrier =================
  // Agent-scope release add: writes back dirty L2 (cast output) before
  // publication. Agent-scope acquire load: invalidates stale L1/L2 lines
  // (incl. last replay's xb/Wb) before the gemm stage reads.
  __syncthreads();
  if (tid == 0) {
    unsigned old = __hip_atomic_fetch_add(&g_bar, 1u, __ATOMIC_RELEASE,
                                          __HIP_MEMORY_SCOPE_AGENT);
    unsigned target = (old / 256u + 1u) * 256u;
    while (__hip_atomic_load(&g_bar, __ATOMIC_ACQUIRE,
                             __HIP_MEMORY_SCOPE_AGENT) < target)
      __builtin_amdgcn_s_sleep(2);
  }
  __syncthreads();

  // ================= stage 1: gemm (round-2 verified) =================
  const unsigned short* __restrict__ A = xb;
  const unsigned short* __restrict__ B = Wb;

  // staging geometry: thread loads 4 A-chunks + 4 B-chunks (16 B each).
  // LDS dest linear (tid*16B + j*8KB); source chunk pre-swizzled: cg = cb^(r&7).
  const int r0 = tid >> 3;                      // 0..63
  const int cg = (tid & 7) ^ (r0 & 7);
  const unsigned short* Ag = A + (size_t)(bm0 + r0) * K_DIM + cg * 8;
  const unsigned short* Bg = B + (size_t)(bn0 + r0) * K_DIM + cg * 8;
  unsigned short* l0 = lds + tid * 8;

#define STAGE(c, t)                                                            \
  do {                                                                         \
    unsigned short* la = l0 + (c) * 32768;                                     \
    const unsigned short* ga = Ag + (t) * BK;                                  \
    const unsigned short* gb = Bg + (t) * BK;                                  \
    _Pragma("unroll")                                                          \
    for (int j = 0; j < 4; ++j) gload_lds16(ga + j * (64 * K_DIM), la + j * 4096); \
    _Pragma("unroll")                                                          \
    for (int j = 0; j < 4; ++j) gload_lds16(gb + j * (64 * K_DIM), la + 16384 + j * 4096); \
  } while (0)

  // fragment LDS offsets (elements); k-half s=1 is offset ^ 32
  const int frow = lane & 15;
  const int q    = lane >> 4;
  int aoff[8], boff[4];
#pragma unroll
  for (int mi = 0; mi < 8; ++mi) {
    int rr = wm * 128 + mi * 16 + frow;
    aoff[mi] = (rr * 8 + (q ^ (rr & 7))) * 8;
  }
#pragma unroll
  for (int ni = 0; ni < 4; ++ni) {
    int rr = wn * 64 + ni * 16 + frow;
    boff[ni] = (rr * 8 + (q ^ (rr & 7))) * 8;
  }

  const int col16 = frow;
  const int row4  = q * 4;
  float bv[4];
#pragma unroll
  for (int ni = 0; ni < 4; ++ni) bv[ni] = bias[bn0 + wn * 64 + ni * 16 + col16];

  f32x4 acc[8][4] = {};

  // prologue: tiles 0 (buf0) and 1 (buf1) in flight; wait tile 0 only.
  STAGE(0, 0);
  STAGE(1, 1);
  asm volatile("s_waitcnt vmcnt(8)" ::: "memory");
  __builtin_amdgcn_s_barrier();

#define PH_OPEN()                                        \
    __builtin_amdgcn_s_barrier();                        \
    asm volatile("s_waitcnt lgkmcnt(0)" ::: "memory");   \
    __builtin_amdgcn_sched_barrier(0);                   \
    __builtin_amdgcn_s_setprio(1)
#define PH_CLOSE()                                       \
    __builtin_amdgcn_s_setprio(0);                       \
    __builtin_amdgcn_sched_barrier(0);                   \
    __builtin_amdgcn_s_barrier()
#define LDA(o) (*(const short8*)(sa + (o)))
#define LDB(o) (*(const short8*)(sb + (o)))

#pragma unroll 2
  for (int t = 0; t < NT; ++t) {
    const unsigned short* sa = lds + (t & 1) * 32768;
    const unsigned short* sb = sa + 16384;
    short8 a[4][2], b01[2][2], b23[2][2];

    // ---------- phase 0 : (m 0-63) x (n 0-31) : 12 ds_reads ----------
#pragma unroll
    for (int mi = 0; mi < 4; ++mi) { a[mi][0] = LDA(aoff[mi]); a[mi][1] = LDA(aoff[mi] ^ 32); }
#pragma unroll
    for (int ni = 0; ni < 2; ++ni) { b01[ni][0] = LDB(boff[ni]); b01[ni][1] = LDB(boff[ni] ^ 32); }
    PH_OPEN();
#pragma unroll
    for (int mi = 0; mi < 4; ++mi)
#pragma unroll
      for (int ni = 0; ni < 2; ++ni)
#pragma unroll
        for (int s = 0; s < 2; ++s)
          acc[mi][ni] = __builtin_amdgcn_mfma_f32_16x16x32_bf16(
              a[mi][s], b01[ni][s], acc[mi][ni], 0, 0, 0);
    PH_CLOSE();

    // ---------- phase 1 : (m 0-63) x (n 32-63) : 4 ds_reads ----------
#pragma unroll
    for (int ni = 0; ni < 2; ++ni) { b23[ni][0] = LDB(boff[ni + 2]); b23[ni][1] = LDB(boff[ni + 2] ^ 32); }
    PH_OPEN();
#pragma unroll
    for (int mi = 0; mi < 4; ++mi)
#pragma unroll
      for (int ni = 0; ni < 2; ++ni)
#pragma unroll
        for (int s = 0; s < 2; ++s)
          acc[mi][ni + 2] = __builtin_amdgcn_mfma_f32_16x16x32_bf16(
              a[mi][s], b23[ni][s], acc[mi][ni + 2], 0, 0, 0);
    PH_CLOSE();

    // ---------- phase 2 : (m 64-127) x (n 0-31) : 8 ds_reads ----------
#pragma unroll
    for (int mi = 0; mi < 4; ++mi) { a[mi][0] = LDA(aoff[mi + 4]); a[mi][1] = LDA(aoff[mi + 4] ^ 32); }
    PH_OPEN();
#pragma unroll
    for (int mi = 0; mi < 4; ++mi)
#pragma unroll
      for (int ni = 0; ni < 2; ++ni)
#pragma unroll
        for (int s = 0; s < 2; ++s)
          acc[mi + 4][ni] = __builtin_amdgcn_mfma_f32_16x16x32_bf16(
              a[mi][s], b01[ni][s], acc[mi + 4][ni], 0, 0, 0);
    PH_CLOSE();

    // ---- phase 3 : (m 64-127) x (n 32-63) + stage tile t+2 ----
    // Staging into buf (t&1) is legal: its ds_reads completed before phase 2's
    // closing barrier. Counted vmcnt(8) AFTER the MFMAs: t+1's 8 loads landed,
    // t+2's 8 stay in flight across the tile boundary.
    if (t + 2 < NT) STAGE(t & 1, t + 2);
    __builtin_amdgcn_sched_barrier(0);
    __builtin_amdgcn_s_setprio(1);
#pragma unroll
    for (int mi = 0; mi < 4; ++mi)
#pragma unroll
      for (int ni = 0; ni < 2; ++ni)
#pragma unroll
        for (int s = 0; s < 2; ++s)
          acc[mi + 4][ni + 2] = __builtin_amdgcn_mfma_f32_16x16x32_bf16(
              a[mi][s], b23[ni][s], acc[mi + 4][ni + 2], 0, 0, 0);
    __builtin_amdgcn_s_setprio(0);
    __builtin_amdgcn_sched_barrier(0);
    if (t + 2 < NT)
      asm volatile("s_waitcnt vmcnt(8)" ::: "memory");
    else
      asm volatile("s_waitcnt vmcnt(0)" ::: "memory");
    __builtin_amdgcn_s_barrier();
  }

  // ---------------- epilogue: C = acc + bias ----------------
#pragma unroll
  for (int ni = 0; ni < 4; ++ni) {
    const int gcol = bn0 + wn * 64 + ni * 16 + col16;
#pragma unroll
    for (int mi = 0; mi < 8; ++mi) {
      const int grow = bm0 + wm * 128 + mi * 16 + row4;
#pragma unroll
      for (int r = 0; r < 4; ++r)
        C[(size_t)(grow + r) * N_DIM + gcol] = acc[mi][ni][r] + bv[ni];
    }
  }
}

extern "C" void kernel_launch(void* const* d_in, const int* in_sizes, int n_in,
                              void* d_out, int out_size, void* d_ws, size_t ws_size,
                              hipStream_t stream) {
  const float* x = (const float*)d_in[0];
  const float* W = (const float*)d_in[1];
  const float* b = (const float*)d_in[2];
  float* out = (float*)d_out;

  unsigned short* xb = (unsigned short*)d_ws;
  unsigned short* Wb = xb + (size_t)M_DIM * K_DIM;

  gemm_fused<<<256, 512, 0, stream>>>(x, W, b, out, xb, Wb);
}